// Round 1
// baseline (7003.951 us; speedup 1.0000x reference)
//
#include <hip/hip_runtime.h>
#include <hip/hip_bf16.h>
#include <math.h>

// Problem constants (from reference)
#define B_    2
#define S_    2048
#define DIM_  4096
#define NH_   32
#define NKV_  8
#define HD_   128
#define REP_  (NH_ / NKV_)          // 4
#define MROWS (B_ * S_)             // 4096 token rows
#define QDIM  (NH_ * HD_)           // 4096
#define KVDIM (NKV_ * HD_)          // 1024

// ---------------------------------------------------------------------------
// Generic f32 GEMM:  C[M,N] = A[M,K] @ W[N,K]^T   (both row-major)
// 128x128 block tile, BK=16, 256 threads, 8x8 accumulators per thread.
// ---------------------------------------------------------------------------
__global__ __launch_bounds__(256, 2) void gemm_bt(const float* __restrict__ A,
                                                  const float* __restrict__ W,
                                                  float* __restrict__ C,
                                                  int M, int N, int K) {
  constexpr int BM = 128, BN = 128, BK = 16;
  __shared__ float As[BK][BM + 4];   // +4 pad: staging-store bank spread
  __shared__ float Bs[BK][BN + 4];
  const int tid = threadIdx.x;
  const int tx = tid & 15;           // 0..15 -> col groups
  const int ty = tid >> 4;           // 0..15 -> row group (8 rows)
  const int row0 = blockIdx.y * BM;
  const int col0 = blockIdx.x * BN;

  float c[8][8] = {};

  for (int k0 = 0; k0 < K; k0 += BK) {
    // Stage A and W tiles (transposed into [k][m]) — 2 float4 each per thread
#pragma unroll
    for (int l = 0; l < 2; ++l) {
      int ci = tid + 256 * l;        // float4 chunk id 0..511
      int m  = ci >> 2;              // 0..127
      int kc = (ci & 3) << 2;        // 0,4,8,12
      float4 a4 = *(const float4*)(A + (size_t)(row0 + m) * K + k0 + kc);
      As[kc + 0][m] = a4.x; As[kc + 1][m] = a4.y;
      As[kc + 2][m] = a4.z; As[kc + 3][m] = a4.w;
      float4 b4 = *(const float4*)(W + (size_t)(col0 + m) * K + k0 + kc);
      Bs[kc + 0][m] = b4.x; Bs[kc + 1][m] = b4.y;
      Bs[kc + 2][m] = b4.z; Bs[kc + 3][m] = b4.w;
    }
    __syncthreads();

#pragma unroll
    for (int kk = 0; kk < BK; ++kk) {
      float4 a0 = *(const float4*)&As[kk][ty * 8];
      float4 a1 = *(const float4*)&As[kk][ty * 8 + 4];
      // cols tx*4..tx*4+3 and tx*4+64..tx*4+67 (split halves: 2-way LDS alias = free)
      float4 b0 = *(const float4*)&Bs[kk][tx * 4];
      float4 b1 = *(const float4*)&Bs[kk][tx * 4 + 64];
      float av[8] = {a0.x, a0.y, a0.z, a0.w, a1.x, a1.y, a1.z, a1.w};
      float bv[8] = {b0.x, b0.y, b0.z, b0.w, b1.x, b1.y, b1.z, b1.w};
#pragma unroll
      for (int i = 0; i < 8; ++i)
#pragma unroll
        for (int j = 0; j < 8; ++j)
          c[i][j] = fmaf(av[i], bv[j], c[i][j]);
    }
    __syncthreads();
  }

#pragma unroll
  for (int i = 0; i < 8; ++i) {
    size_t r = (size_t)(row0 + ty * 8 + i);
    float4 v0 = make_float4(c[i][0], c[i][1], c[i][2], c[i][3]);
    float4 v1 = make_float4(c[i][4], c[i][5], c[i][6], c[i][7]);
    *(float4*)(C + r * N + col0 + tx * 4)      = v0;
    *(float4*)(C + r * N + col0 + tx * 4 + 64) = v1;
  }
}

// ---------------------------------------------------------------------------
// RoPE applied in-place to q (NH heads) and k (NKV heads).
// One thread per (row, pair). Wave-uniform q/k branch (t = idx>>6 const/wave).
// ---------------------------------------------------------------------------
__global__ void rope_kernel(float* __restrict__ q, float* __restrict__ kbuf,
                            const float* __restrict__ cs,
                            const float* __restrict__ sn) {
  int idx = blockIdx.x * 256 + threadIdx.x;
  int j  = idx & 63;                 // pair index 0..63
  int t  = idx >> 6;                 // head-row id
  int hh = t % (NH_ + NKV_);
  int bs = t / (NH_ + NKV_);         // 0..MROWS-1
  int s  = bs & (S_ - 1);
  float c  = cs[s * 64 + j];
  float si = sn[s * 64 + j];
  float* p = (hh < NH_)
      ? q    + (size_t)bs * QDIM  + hh * HD_          + 2 * j
      : kbuf + (size_t)bs * KVDIM + (hh - NH_) * HD_  + 2 * j;
  float xr = p[0], xi = p[1];
  p[0] = xr * c - xi * si;
  p[1] = xr * si + xi * c;
}

// ---------------------------------------------------------------------------
// Causal GQA flash attention, f32. One block per (q-tile of 32, head, batch).
// Online softmax; O accumulators in registers (each thread: row r=tid>>3,
// dims d = 32*dd + 4*(tid&7) + u).
// ---------------------------------------------------------------------------
__global__ __launch_bounds__(256, 2) void attn_kernel(
    const float* __restrict__ q, const float* __restrict__ kbuf,
    const float* __restrict__ vbuf, float* __restrict__ o) {
  constexpr int BQ = 32, BKV = 32, PD = HD_ + 4;   // 132: bank-spread pad
  __shared__ float Qs[BQ][PD];
  __shared__ float Ks[BKV][PD];
  __shared__ float Vs[BKV][PD];
  __shared__ float Ps[BQ][BKV + 1];                // +1: softmax column reads
  __shared__ float mrow[BQ], lrow[BQ], arow[BQ];

  const int tid = threadIdx.x;
  const int qt = blockIdx.x, h = blockIdx.y, b = blockIdx.z;
  const int kvh = h >> 2;                          // REP_ = 4
  const int q0 = qt * BQ;
  const int r  = tid >> 3;                         // q-row in tile 0..31
  const int c0 = tid & 7;                          // col/dim group 0..7
  const float scale = 0.08838834764831845f;        // 1/sqrt(128)

  // Load Q tile (32 x 128) once
#pragma unroll
  for (int l = 0; l < 4; ++l) {
    int ci = tid + 256 * l;                        // float4 idx 0..1023
    int rr = ci >> 5;
    int d4 = (ci & 31) << 2;
    *(float4*)&Qs[rr][d4] =
        *(const float4*)(q + (size_t)(b * S_ + q0 + rr) * QDIM + h * HD_ + d4);
  }
  if (tid < BQ) { mrow[tid] = -INFINITY; lrow[tid] = 0.f; }

  float oacc[4][4] = {};                           // [dd][u]

  for (int kt = 0; kt <= qt; ++kt) {
    __syncthreads();                               // protect K/V/P from prev iter
    // Stage K and V tiles
#pragma unroll
    for (int l = 0; l < 4; ++l) {
      int ci = tid + 256 * l;
      int rr = ci >> 5;
      int d4 = (ci & 31) << 2;
      size_t g = (size_t)(b * S_ + kt * BKV + rr) * KVDIM + kvh * HD_ + d4;
      *(float4*)&Ks[rr][d4] = *(const float4*)(kbuf + g);
      *(float4*)&Vs[rr][d4] = *(const float4*)(vbuf + g);
    }
    __syncthreads();

    // Scores: thread computes row r, cols {c0 + 8*cc} (bank-conflict-free K reads)
    {
      float acc[4] = {0.f, 0.f, 0.f, 0.f};
#pragma unroll 4
      for (int kk = 0; kk < HD_; kk += 4) {
        float4 q4 = *(const float4*)&Qs[r][kk];
#pragma unroll
        for (int cc = 0; cc < 4; ++cc) {
          float4 k4 = *(const float4*)&Ks[c0 + 8 * cc][kk];
          acc[cc] = fmaf(q4.x, k4.x, acc[cc]);
          acc[cc] = fmaf(q4.y, k4.y, acc[cc]);
          acc[cc] = fmaf(q4.z, k4.z, acc[cc]);
          acc[cc] = fmaf(q4.w, k4.w, acc[cc]);
        }
      }
      int qi = q0 + r;
#pragma unroll
      for (int cc = 0; cc < 4; ++cc) {
        int ki = kt * BKV + c0 + 8 * cc;
        Ps[r][c0 + 8 * cc] = (ki <= qi) ? acc[cc] * scale : -INFINITY;
      }
    }
    __syncthreads();

    // Online softmax per row (threads 0..31, one row each)
    if (tid < BQ) {
      float m_old = mrow[tid];
      float mx = m_old;
#pragma unroll
      for (int j = 0; j < BKV; ++j) mx = fmaxf(mx, Ps[tid][j]);
      float alpha = __expf(m_old - mx);            // -inf - finite -> 0
      float sum = 0.f;
#pragma unroll
      for (int j = 0; j < BKV; ++j) {
        float p = __expf(Ps[tid][j] - mx);
        Ps[tid][j] = p;
        sum += p;
      }
      lrow[tid] = lrow[tid] * alpha + sum;
      mrow[tid] = mx;
      arow[tid] = alpha;
    }
    __syncthreads();

    // O update: o[r][d] = o*alpha + sum_j p[r][j] * V[j][d]
    float alpha = arow[r];
#pragma unroll
    for (int dd = 0; dd < 4; ++dd)
#pragma unroll
      for (int u = 0; u < 4; ++u) oacc[dd][u] *= alpha;
    for (int j = 0; j < BKV; ++j) {
      float p = Ps[r][j];
#pragma unroll
      for (int dd = 0; dd < 4; ++dd) {
        float4 v4 = *(const float4*)&Vs[j][32 * dd + 4 * c0];
        oacc[dd][0] = fmaf(p, v4.x, oacc[dd][0]);
        oacc[dd][1] = fmaf(p, v4.y, oacc[dd][1]);
        oacc[dd][2] = fmaf(p, v4.z, oacc[dd][2]);
        oacc[dd][3] = fmaf(p, v4.w, oacc[dd][3]);
      }
    }
  }

  // Epilogue: normalize and store to attn buffer laid out (b, s, h, d)
  float linv = 1.0f / lrow[r];
  float* ob = o + (size_t)(b * S_ + q0 + r) * QDIM + h * HD_;
#pragma unroll
  for (int dd = 0; dd < 4; ++dd) {
    float4 v4 = make_float4(oacc[dd][0] * linv, oacc[dd][1] * linv,
                            oacc[dd][2] * linv, oacc[dd][3] * linv);
    *(float4*)(ob + 32 * dd + 4 * c0) = v4;
  }
}

// ---------------------------------------------------------------------------
// Launch: QKV GEMMs -> RoPE -> flash attention -> output GEMM
// Workspace: q (64MB) | k (16MB) | v (16MB) | attn (64MB) = 160 MiB
// ---------------------------------------------------------------------------
extern "C" void kernel_launch(void* const* d_in, const int* in_sizes, int n_in,
                              void* d_out, int out_size, void* d_ws, size_t ws_size,
                              hipStream_t stream) {
  const float* x  = (const float*)d_in[0];
  const float* wq = (const float*)d_in[1];
  const float* wk = (const float*)d_in[2];
  const float* wv = (const float*)d_in[3];
  const float* wo = (const float*)d_in[4];
  const float* fc = (const float*)d_in[5];
  const float* fs = (const float*)d_in[6];
  // d_in[7] = start_pos (always 0 in this problem; reference ignores it)
  float* out = (float*)d_out;

  float* qb   = (float*)d_ws;
  float* kb   = qb + (size_t)MROWS * QDIM;
  float* vb   = kb + (size_t)MROWS * KVDIM;
  float* attn = vb + (size_t)MROWS * KVDIM;

  dim3 blk(256);

  // Projections
  gemm_bt<<<dim3(QDIM / 128,  MROWS / 128), blk, 0, stream>>>(x, wq, qb, MROWS, QDIM,  DIM_);
  gemm_bt<<<dim3(KVDIM / 128, MROWS / 128), blk, 0, stream>>>(x, wk, kb, MROWS, KVDIM, DIM_);
  gemm_bt<<<dim3(KVDIM / 128, MROWS / 128), blk, 0, stream>>>(x, wv, vb, MROWS, KVDIM, DIM_);

  // RoPE on q and k, in place
  int pairs = B_ * S_ * (NH_ + NKV_) * (HD_ / 2);
  rope_kernel<<<pairs / 256, blk, 0, stream>>>(qb, kb, fc, fs);

  // Causal GQA attention
  attn_kernel<<<dim3(S_ / 32, NH_, B_), blk, 0, stream>>>(qb, kb, vb, attn);

  // Output projection
  gemm_bt<<<dim3(QDIM / 128, MROWS / 128), blk, 0, stream>>>(attn, wo, out, MROWS, QDIM, DIM_);
}

// Round 2
// 1226.269 us; speedup vs baseline: 5.7116x; 5.7116x over previous
//
#include <hip/hip_runtime.h>
#include <math.h>

// Problem constants
#define B_    2
#define S_    2048
#define DIM_  4096
#define NH_   32
#define NKV_  8
#define HD_   128
#define MROWS (B_ * S_)             // 4096
#define QDIM  (NH_ * HD_)           // 4096
#define KVDIM (NKV_ * HD_)          // 1024

typedef unsigned short ushort_t;
typedef __attribute__((ext_vector_type(8))) short bf16x8;   // 8 bf16 = 4 VGPRs
typedef __attribute__((ext_vector_type(4))) float f32x4;    // MFMA 16x16 accum

#define MFMA16(a, b, c) __builtin_amdgcn_mfma_f32_16x16x32_bf16(a, b, c, 0, 0, 0)

__device__ __forceinline__ float bf2f(ushort_t u) {
  return __uint_as_float(((unsigned int)u) << 16);
}
__device__ __forceinline__ ushort_t f2bf(float f) {
  unsigned int x = __float_as_uint(f);
  return (ushort_t)((x + 0x7fffu + ((x >> 16) & 1u)) >> 16);  // RNE
}
// Async global->LDS, 16B per lane. LDS dst must be wave-uniform base; HW adds lane*16.
__device__ __forceinline__ void gload16(const void* g, void* l) {
  __builtin_amdgcn_global_load_lds(
      (const __attribute__((address_space(1))) void*)g,
      (__attribute__((address_space(3))) void*)l, 16, 0, 0);
}

// ---------------------------------------------------------------------------
// f32 -> bf16 convert, 8 elems/thread
// ---------------------------------------------------------------------------
__global__ void conv_f32_bf16(const float* __restrict__ in,
                              ushort_t* __restrict__ out) {
  int i = blockIdx.x * 256 + threadIdx.x;
  float4 a = ((const float4*)in)[i * 2 + 0];
  float4 b = ((const float4*)in)[i * 2 + 1];
  bf16x8 o;
  o[0] = (short)f2bf(a.x); o[1] = (short)f2bf(a.y);
  o[2] = (short)f2bf(a.z); o[3] = (short)f2bf(a.w);
  o[4] = (short)f2bf(b.x); o[5] = (short)f2bf(b.y);
  o[6] = (short)f2bf(b.z); o[7] = (short)f2bf(b.w);
  ((bf16x8*)out)[i] = o;
}

// ---------------------------------------------------------------------------
// bf16 MFMA GEMM: C[M,N] = A[M,K] @ W[N,K]^T, A/W bf16 row-major.
// 128x128 tile, BK=32, 256 thr = 4 waves, each wave 64x64 (4x4 MFMA tiles).
// OUT_MODE 0: bf16 row-major; 1: f32 row-major; 2: bf16 transposed (C^T, ld=M)
// ---------------------------------------------------------------------------
template <int OUT_MODE>
__global__ __launch_bounds__(256, 2) void gemm_bf16(
    const ushort_t* __restrict__ A, const ushort_t* __restrict__ W,
    void* __restrict__ Cv, int M, int N, int K) {
  constexpr int BK = 32;
  __shared__ ushort_t As[128 * BK];   // [m][k] row stride 64B
  __shared__ ushort_t Ws[128 * BK];   // [n][k]
  const int tid = threadIdx.x, lane = tid & 63, w = tid >> 6;
  const int quad = lane >> 4, l16 = lane & 15;
  const int row0 = blockIdx.y * 128, col0 = blockIdx.x * 128;
  const int wm = (w & 1) * 64, wn = (w >> 1) * 64;

  f32x4 acc[4][4] = {};

  for (int k0 = 0; k0 < K; k0 += BK) {
    __syncthreads();
#pragma unroll
    for (int i = 0; i < 2; ++i) {
      int c = i * 256 + w * 64 + lane;          // 16B chunk id, 4 chunks/row
      int r = c >> 2, ko = (c & 3) * 8;
      gload16(A + (size_t)(row0 + r) * K + k0 + ko,
              (char*)As + (i * 256 + w * 64) * 16);
      gload16(W + (size_t)(col0 + r) * K + k0 + ko,
              (char*)Ws + (i * 256 + w * 64) * 16);
    }
    __syncthreads();

    bf16x8 af[4], bfr[4];
#pragma unroll
    for (int mt = 0; mt < 4; ++mt)
      af[mt] = *(const bf16x8*)((char*)As + (wm + mt * 16 + l16) * 64 + quad * 16);
#pragma unroll
    for (int nt = 0; nt < 4; ++nt)
      bfr[nt] = *(const bf16x8*)((char*)Ws + (wn + nt * 16 + l16) * 64 + quad * 16);
#pragma unroll
    for (int mt = 0; mt < 4; ++mt)
#pragma unroll
      for (int nt = 0; nt < 4; ++nt)
        acc[mt][nt] = MFMA16(af[mt], bfr[nt], acc[mt][nt]);
  }

#pragma unroll
  for (int mt = 0; mt < 4; ++mt)
#pragma unroll
    for (int nt = 0; nt < 4; ++nt)
#pragma unroll
      for (int r = 0; r < 4; ++r) {
        int row = row0 + wm + mt * 16 + quad * 4 + r;
        int col = col0 + wn + nt * 16 + l16;
        float v = acc[mt][nt][r];
        if (OUT_MODE == 0)
          ((ushort_t*)Cv)[(size_t)row * N + col] = f2bf(v);
        else if (OUT_MODE == 1)
          ((float*)Cv)[(size_t)row * N + col] = v;
        else
          ((ushort_t*)Cv)[(size_t)col * M + row] = f2bf(v);  // C^T
      }
}

// ---------------------------------------------------------------------------
// RoPE in place on bf16 q [MROWS][QDIM] and k [MROWS][KVDIM].
// Thread handles 4 pairs (8 bf16 = 16B). 16 threads per head-row.
// ---------------------------------------------------------------------------
__global__ void rope_bf16(ushort_t* __restrict__ q, ushort_t* __restrict__ k,
                          const float* __restrict__ cs,
                          const float* __restrict__ sn) {
  int idx = blockIdx.x * 256 + threadIdx.x;
  int jg = (idx & 15) * 4;           // pair group base (pairs jg..jg+3)
  int t = idx >> 4;                  // head-row id
  int hh = t % (NH_ + NKV_);
  int bs = t / (NH_ + NKV_);
  int s = bs & (S_ - 1);
  float4 c4 = *(const float4*)(cs + s * 64 + jg);
  float4 s4 = *(const float4*)(sn + s * 64 + jg);
  ushort_t* p = (hh < NH_)
      ? q + (size_t)bs * QDIM + hh * HD_ + 2 * jg
      : k + (size_t)bs * KVDIM + (hh - NH_) * HD_ + 2 * jg;
  bf16x8 v = *(const bf16x8*)p;
  float cc[4] = {c4.x, c4.y, c4.z, c4.w};
  float ss[4] = {s4.x, s4.y, s4.z, s4.w};
  bf16x8 o;
#pragma unroll
  for (int u = 0; u < 4; ++u) {
    float xr = bf2f((ushort_t)v[2 * u]);
    float xi = bf2f((ushort_t)v[2 * u + 1]);
    o[2 * u]     = (short)f2bf(xr * cc[u] - xi * ss[u]);
    o[2 * u + 1] = (short)f2bf(xr * ss[u] + xi * cc[u]);
  }
  *(bf16x8*)p = o;
}

// ---------------------------------------------------------------------------
// MFMA flash attention (causal, GQA). Block = 256 thr = 4 waves; BQ=64 (16
// q-rows per wave), BKV=32, HD=128. Online softmax in registers (C/D row
// layout: rows = quad*4+r). V is read pre-transposed: vt[KVDIM][MROWS].
// ---------------------------------------------------------------------------
__global__ __launch_bounds__(256, 2) void attn_mfma(
    const ushort_t* __restrict__ qb, const ushort_t* __restrict__ kb,
    const ushort_t* __restrict__ vt, ushort_t* __restrict__ ob) {
  constexpr int BQ = 64, BKV = 32;
  __shared__ ushort_t KV[8192];          // 16KB: Ks[32][128] | Vt[128][32]; Q staging at start
  __shared__ ushort_t Ps[4 * 16 * 40];   // per-wave P tile [16][40] (80B rows, 16B-aligned)

  const int tid = threadIdx.x, lane = tid & 63, w = tid >> 6;
  const int quad = lane >> 4, l16 = lane & 15;
  const int qt = blockIdx.x, h = blockIdx.y, b = blockIdx.z;
  const int kvh = h >> 2;
  const int q0 = qt * BQ;
  const float scale = 0.08838834764831845f;   // 1/sqrt(128)

  // Stage Q[64][128] bf16 (16KB) then pull this wave's fragments to registers.
#pragma unroll
  for (int i = 0; i < 4; ++i) {
    int c = i * 256 + w * 64 + lane;     // row = c>>4 (16 chunks/row)
    gload16(qb + (size_t)(b * S_ + q0 + (c >> 4)) * QDIM + h * HD_ + (c & 15) * 8,
            (char*)KV + (i * 256 + w * 64) * 16);
  }
  __syncthreads();
  bf16x8 qf[4];
#pragma unroll
  for (int t = 0; t < 4; ++t)
    qf[t] = *(const bf16x8*)((char*)KV + (w * 16 + l16) * 256 + t * 64 + quad * 16);

  float m_[4], l_[4];
  f32x4 o_[8] = {};
#pragma unroll
  for (int r = 0; r < 4; ++r) { m_[r] = -1e30f; l_[r] = 0.f; }

  const int ktmax = 2 * qt + 1;
  for (int kt = 0; kt <= ktmax; ++kt) {
    __syncthreads();                     // protect KV from previous iter reads
    // Stage K rows (8KB) and V^T rows (8KB)
#pragma unroll
    for (int i = 0; i < 2; ++i) {
      int c = i * 256 + w * 64 + lane;
      gload16(kb + (size_t)(b * S_ + kt * BKV + (c >> 4)) * KVDIM + kvh * HD_ + (c & 15) * 8,
              (char*)KV + (i * 256 + w * 64) * 16);
      gload16(vt + (size_t)(kvh * HD_ + (c >> 2)) * MROWS + b * S_ + kt * BKV + (c & 3) * 8,
              (char*)KV + 8192 + (i * 256 + w * 64) * 16);
    }
    __syncthreads();

    // S = Q K^T for this wave's 16 rows x 32 kv cols (two 16x16 tiles)
    f32x4 s[2];
#pragma unroll
    for (int nt = 0; nt < 2; ++nt) {
      f32x4 a = {0.f, 0.f, 0.f, 0.f};
#pragma unroll
      for (int t = 0; t < 4; ++t) {
        bf16x8 kf = *(const bf16x8*)((char*)KV + (nt * 16 + l16) * 256 + t * 64 + quad * 16);
        a = MFMA16(qf[t], kf, a);
      }
      s[nt] = a;
    }

    // mask + scale + online softmax (rows = quad*4+r; cols = l16 per tile)
    const int qrow = q0 + w * 16 + quad * 4;
    float p0v[4], p1v[4], alpha[4];
#pragma unroll
    for (int r = 0; r < 4; ++r) {
      float s0 = s[0][r] * scale, s1 = s[1][r] * scale;
      int kv0 = kt * BKV + l16;
      if (kv0 > qrow + r) s0 = -INFINITY;
      if (kv0 + 16 > qrow + r) s1 = -INFINITY;
      float mx = fmaxf(s0, s1);
#pragma unroll
      for (int d = 1; d < 16; d <<= 1) mx = fmaxf(mx, __shfl_xor(mx, d, 64));
      float mnew = fmaxf(m_[r], mx);
      alpha[r] = __expf(m_[r] - mnew);
      float p0 = __expf(s0 - mnew), p1 = __expf(s1 - mnew);
      float sum = p0 + p1;
#pragma unroll
      for (int d = 1; d < 16; d <<= 1) sum += __shfl_xor(sum, d, 64);
      l_[r] = l_[r] * alpha[r] + sum;
      m_[r] = mnew;
      p0v[r] = p0; p1v[r] = p1;
    }
#pragma unroll
    for (int dt = 0; dt < 8; ++dt)
#pragma unroll
      for (int r = 0; r < 4; ++r) o_[dt][r] *= alpha[r];

    // P -> LDS (C/D layout -> A-operand layout round trip)
    ushort_t* psw = Ps + w * 640;
#pragma unroll
    for (int r = 0; r < 4; ++r) {
      psw[(quad * 4 + r) * 40 + l16] = f2bf(p0v[r]);
      psw[(quad * 4 + r) * 40 + 16 + l16] = f2bf(p1v[r]);
    }
    __syncthreads();
    bf16x8 pf = *(const bf16x8*)((char*)psw + l16 * 80 + quad * 16);

    // O += P V  (8 d-tiles of 16)
#pragma unroll
    for (int dt = 0; dt < 8; ++dt) {
      bf16x8 vf = *(const bf16x8*)((char*)KV + 8192 + (dt * 16 + l16) * 64 + quad * 16);
      o_[dt] = MFMA16(pf, vf, o_[dt]);
    }
  }

  // epilogue: normalize, store bf16 to attn buffer (b,s,h,d)
#pragma unroll
  for (int r = 0; r < 4; ++r) {
    float linv = 1.0f / l_[r];
    size_t base = (size_t)(b * S_ + q0 + w * 16 + quad * 4 + r) * QDIM + h * HD_;
#pragma unroll
    for (int dt = 0; dt < 8; ++dt)
      ob[base + dt * 16 + l16] = f2bf(o_[dt][r] * linv);
  }
}

// ---------------------------------------------------------------------------
// Launch. Workspace layout (MiB offsets), 160 MiB total:
//   0: xb(32, reused for wob) | 32: wqb(32) | 64: wkb(8) | 72: wvb(8)
//  80: qbuf(32) | 112: kbuf(8) | 120: vtb(8) | 128: attnb(32)
// ---------------------------------------------------------------------------
extern "C" void kernel_launch(void* const* d_in, const int* in_sizes, int n_in,
                              void* d_out, int out_size, void* d_ws, size_t ws_size,
                              hipStream_t stream) {
  const float* x  = (const float*)d_in[0];
  const float* wq = (const float*)d_in[1];
  const float* wk = (const float*)d_in[2];
  const float* wv = (const float*)d_in[3];
  const float* wo = (const float*)d_in[4];
  const float* fc = (const float*)d_in[5];
  const float* fs = (const float*)d_in[6];
  float* out = (float*)d_out;

  char* ws = (char*)d_ws;
  ushort_t* xb    = (ushort_t*)(ws);
  ushort_t* wqb   = (ushort_t*)(ws + (32ull << 20));
  ushort_t* wkb   = (ushort_t*)(ws + (64ull << 20));
  ushort_t* wvb   = (ushort_t*)(ws + (72ull << 20));
  ushort_t* qbuf  = (ushort_t*)(ws + (80ull << 20));
  ushort_t* kbuf  = (ushort_t*)(ws + (112ull << 20));
  ushort_t* vtb   = (ushort_t*)(ws + (120ull << 20));
  ushort_t* attnb = (ushort_t*)(ws + (128ull << 20));
  ushort_t* wob   = xb;  // x dead after projections

  dim3 blk(256);

  // bf16 conversions (x + q/k/v weights)
  conv_f32_bf16<<<(MROWS * DIM_) / 2048, blk, 0, stream>>>(x, xb);
  conv_f32_bf16<<<(QDIM * DIM_) / 2048, blk, 0, stream>>>(wq, wqb);
  conv_f32_bf16<<<(KVDIM * DIM_) / 2048, blk, 0, stream>>>(wk, wkb);
  conv_f32_bf16<<<(KVDIM * DIM_) / 2048, blk, 0, stream>>>(wv, wvb);

  // Projections (V written transposed for attention staging)
  gemm_bf16<0><<<dim3(QDIM / 128, MROWS / 128), blk, 0, stream>>>(xb, wqb, qbuf, MROWS, QDIM, DIM_);
  gemm_bf16<0><<<dim3(KVDIM / 128, MROWS / 128), blk, 0, stream>>>(xb, wkb, kbuf, MROWS, KVDIM, DIM_);
  gemm_bf16<2><<<dim3(KVDIM / 128, MROWS / 128), blk, 0, stream>>>(xb, wvb, vtb, MROWS, KVDIM, DIM_);

  // RoPE in place on q/k
  rope_bf16<<<(MROWS * (NH_ + NKV_) * 16) / 256, blk, 0, stream>>>(qbuf, kbuf, fc, fs);

  // Flash attention
  attn_mfma<<<dim3(S_ / 64, NH_, B_), blk, 0, stream>>>(qbuf, kbuf, vtb, attnb);

  // Output projection (f32 out) — convert wo late, into xb's space
  conv_f32_bf16<<<(QDIM * DIM_) / 2048, blk, 0, stream>>>(wo, wob);
  gemm_bf16<1><<<dim3(QDIM / 128, MROWS / 128), blk, 0, stream>>>(attnb, wob, out, MROWS, QDIM, DIM_);
}

// Round 3
// 992.684 us; speedup vs baseline: 7.0556x; 1.2353x over previous
//
#include <hip/hip_runtime.h>
#include <math.h>

// Problem constants
#define B_    2
#define S_    2048
#define DIM_  4096
#define NH_   32
#define NKV_  8
#define HD_   128
#define MROWS (B_ * S_)             // 4096
#define QDIM  (NH_ * HD_)           // 4096
#define KVDIM (NKV_ * HD_)          // 1024

typedef unsigned short ushort_t;
typedef __attribute__((ext_vector_type(8))) short bf16x8;   // 8 bf16 = 4 VGPRs
typedef __attribute__((ext_vector_type(4))) float f32x4;    // MFMA 16x16 accum

#define MFMA16(a, b, c) __builtin_amdgcn_mfma_f32_16x16x32_bf16(a, b, c, 0, 0, 0)

__device__ __forceinline__ float bf2f(ushort_t u) {
  return __uint_as_float(((unsigned int)u) << 16);
}
__device__ __forceinline__ ushort_t f2bf(float f) {
  unsigned int x = __float_as_uint(f);
  return (ushort_t)((x + 0x7fffu + ((x >> 16) & 1u)) >> 16);  // RNE
}
// Async global->LDS, 16B per lane. LDS dst is wave-uniform base; HW adds lane*16.
__device__ __forceinline__ void gload16(const void* g, void* l) {
  __builtin_amdgcn_global_load_lds(
      (const __attribute__((address_space(1))) void*)g,
      (__attribute__((address_space(3))) void*)l, 16, 0, 0);
}

// ---------------------------------------------------------------------------
// f32 -> bf16 convert, 8 elems/thread
// ---------------------------------------------------------------------------
__global__ void conv_f32_bf16(const float* __restrict__ in,
                              ushort_t* __restrict__ out) {
  int i = blockIdx.x * 256 + threadIdx.x;
  float4 a = ((const float4*)in)[i * 2 + 0];
  float4 b = ((const float4*)in)[i * 2 + 1];
  bf16x8 o;
  o[0] = (short)f2bf(a.x); o[1] = (short)f2bf(a.y);
  o[2] = (short)f2bf(a.z); o[3] = (short)f2bf(a.w);
  o[4] = (short)f2bf(b.x); o[5] = (short)f2bf(b.y);
  o[6] = (short)f2bf(b.z); o[7] = (short)f2bf(b.w);
  ((bf16x8*)out)[i] = o;
}

// ---------------------------------------------------------------------------
// bf16 MFMA GEMM: C[M,N] = A[M,K] @ W[N,K]^T (m97-class structure, unchanged)
// ---------------------------------------------------------------------------
template <int OUT_MODE>
__global__ __launch_bounds__(256, 2) void gemm_bf16(
    const ushort_t* __restrict__ A, const ushort_t* __restrict__ W,
    void* __restrict__ Cv, int M, int N, int K) {
  constexpr int BK = 32;
  __shared__ ushort_t As[128 * BK];   // [m][k] row stride 64B
  __shared__ ushort_t Ws[128 * BK];   // [n][k]
  const int tid = threadIdx.x, lane = tid & 63, w = tid >> 6;
  const int quad = lane >> 4, l16 = lane & 15;
  const int row0 = blockIdx.y * 128, col0 = blockIdx.x * 128;
  const int wm = (w & 1) * 64, wn = (w >> 1) * 64;

  f32x4 acc[4][4] = {};

  for (int k0 = 0; k0 < K; k0 += BK) {
    __syncthreads();
#pragma unroll
    for (int i = 0; i < 2; ++i) {
      int c = i * 256 + w * 64 + lane;          // 16B chunk id, 4 chunks/row
      int r = c >> 2, ko = (c & 3) * 8;
      gload16(A + (size_t)(row0 + r) * K + k0 + ko,
              (char*)As + (i * 256 + w * 64) * 16);
      gload16(W + (size_t)(col0 + r) * K + k0 + ko,
              (char*)Ws + (i * 256 + w * 64) * 16);
    }
    __syncthreads();

    bf16x8 af[4], bfr[4];
#pragma unroll
    for (int mt = 0; mt < 4; ++mt)
      af[mt] = *(const bf16x8*)((char*)As + (wm + mt * 16 + l16) * 64 + quad * 16);
#pragma unroll
    for (int nt = 0; nt < 4; ++nt)
      bfr[nt] = *(const bf16x8*)((char*)Ws + (wn + nt * 16 + l16) * 64 + quad * 16);
#pragma unroll
    for (int mt = 0; mt < 4; ++mt)
#pragma unroll
      for (int nt = 0; nt < 4; ++nt)
        acc[mt][nt] = MFMA16(af[mt], bfr[nt], acc[mt][nt]);
  }

#pragma unroll
  for (int mt = 0; mt < 4; ++mt)
#pragma unroll
    for (int nt = 0; nt < 4; ++nt)
#pragma unroll
      for (int r = 0; r < 4; ++r) {
        int row = row0 + wm + mt * 16 + quad * 4 + r;
        int col = col0 + wn + nt * 16 + l16;
        float v = acc[mt][nt][r];
        if (OUT_MODE == 0)
          ((ushort_t*)Cv)[(size_t)row * N + col] = f2bf(v);
        else if (OUT_MODE == 1)
          ((float*)Cv)[(size_t)row * N + col] = v;
        else
          ((ushort_t*)Cv)[(size_t)col * M + row] = f2bf(v);  // C^T
      }
}

// ---------------------------------------------------------------------------
// RoPE in place on bf16 q and k (unchanged)
// ---------------------------------------------------------------------------
__global__ void rope_bf16(ushort_t* __restrict__ q, ushort_t* __restrict__ k,
                          const float* __restrict__ cs,
                          const float* __restrict__ sn) {
  int idx = blockIdx.x * 256 + threadIdx.x;
  int jg = (idx & 15) * 4;
  int t = idx >> 4;
  int hh = t % (NH_ + NKV_);
  int bs = t / (NH_ + NKV_);
  int s = bs & (S_ - 1);
  float4 c4 = *(const float4*)(cs + s * 64 + jg);
  float4 s4 = *(const float4*)(sn + s * 64 + jg);
  ushort_t* p = (hh < NH_)
      ? q + (size_t)bs * QDIM + hh * HD_ + 2 * jg
      : k + (size_t)bs * KVDIM + (hh - NH_) * HD_ + 2 * jg;
  bf16x8 v = *(const bf16x8*)p;
  float cc[4] = {c4.x, c4.y, c4.z, c4.w};
  float ss[4] = {s4.x, s4.y, s4.z, s4.w};
  bf16x8 o;
#pragma unroll
  for (int u = 0; u < 4; ++u) {
    float xr = bf2f((ushort_t)v[2 * u]);
    float xi = bf2f((ushort_t)v[2 * u + 1]);
    o[2 * u]     = (short)f2bf(xr * cc[u] - xi * ss[u]);
    o[2 * u + 1] = (short)f2bf(xr * ss[u] + xi * cc[u]);
  }
  *(bf16x8*)p = o;
}

// ---------------------------------------------------------------------------
// MFMA flash attention v2. Block = 4 waves; BQ=64 (16 q-rows/wave), BKV=64.
// XOR-swizzled LDS: Q/K rows 256B/16 chunks (c^=r&15), V^T rows 128B/8 chunks
// (c^=r&7) -> fragment ds_read_b128 are ~2-way aliased (free). P per-wave,
// rows padded to 144B. Diagonal tiles skip nt>w; masking only on kt==qt.
// ---------------------------------------------------------------------------
__global__ __launch_bounds__(256, 2) void attn_mfma(
    const ushort_t* __restrict__ qb, const ushort_t* __restrict__ kb,
    const ushort_t* __restrict__ vt, ushort_t* __restrict__ ob) {
  __shared__ __align__(16) char smem[16384 + 16384 + 4 * 2304];
  char* Ks = smem;                    // 64 rows x 256B (swizzled), also Q staging
  char* Vs = smem + 16384;            // 128 rows x 128B (swizzled)
  const int tid = threadIdx.x, lane = tid & 63, w = tid >> 6;
  const int quad = lane >> 4, l16 = lane & 15;
  char* psw = smem + 32768 + w * 2304;   // per-wave P: 16 rows x 144B
  const int qt = blockIdx.x, h = blockIdx.y, b = blockIdx.z;
  const int kvh = h >> 2;
  const int q0 = qt * 64;
  const float C = 0.12756113f;        // (1/sqrt(128)) * log2(e)

  // ---- stage Q[64][128] into Ks region (swizzled), pull fragments ----
#pragma unroll
  for (int i = 0; i < 4; ++i) {
    int r0 = w * 16 + i * 4;
    int r = r0 + (lane >> 4);
    int c = (lane & 15) ^ (r & 15);
    gload16(qb + (size_t)(b * S_ + q0 + r) * QDIM + h * HD_ + c * 8,
            Ks + r0 * 256);
  }
  __syncthreads();
  bf16x8 qf[4];
#pragma unroll
  for (int t = 0; t < 4; ++t)
    qf[t] = *(const bf16x8*)(Ks + (w * 16 + l16) * 256 + (((t * 4 + quad) ^ l16) * 16));

  float m_[4], l_[4];
  f32x4 o_[8] = {};
#pragma unroll
  for (int r = 0; r < 4; ++r) { m_[r] = -1e30f; l_[r] = 0.f; }

  for (int kt = 0; kt <= qt; ++kt) {
    __syncthreads();                  // prior iteration's reads done
    // ---- stage K[64][128] and V^T[128][64] (swizzled) ----
#pragma unroll
    for (int i = 0; i < 4; ++i) {
      int r0 = w * 16 + i * 4;
      int r = r0 + (lane >> 4);
      int c = (lane & 15) ^ (r & 15);
      gload16(kb + (size_t)(b * S_ + kt * 64 + r) * KVDIM + kvh * HD_ + c * 8,
              Ks + r0 * 256);
      int vr0 = w * 32 + i * 8;
      int vr = vr0 + (lane >> 3);
      int vc = (lane & 7) ^ (vr & 7);
      gload16(vt + (size_t)(kvh * HD_ + vr) * MROWS + b * S_ + kt * 64 + vc * 8,
              Vs + vr0 * 128);
    }
    __syncthreads();

    // ---- S = Q K^T : 4 kv tiles of 16 (skip fully-masked tiles on diag) ----
    const int ntmax = (kt == qt) ? w : 3;
    f32x4 s[4];
#pragma unroll
    for (int nt = 0; nt < 4; ++nt) {
      if (nt <= ntmax) {
        f32x4 a = {0.f, 0.f, 0.f, 0.f};
#pragma unroll
        for (int t = 0; t < 4; ++t) {
          bf16x8 kf = *(const bf16x8*)(Ks + (nt * 16 + l16) * 256 +
                                       (((t * 4 + quad) ^ l16) * 16));
          a = MFMA16(qf[t], kf, a);
        }
        s[nt] = a;
      } else {
        s[nt] = (f32x4){-INFINITY, -INFINITY, -INFINITY, -INFINITY};
      }
    }

    // ---- online softmax (exp2 domain; rows = quad*4+r, cols = l16) ----
    float p[4][4], al[4];
#pragma unroll
    for (int r = 0; r < 4; ++r) {
      float v[4];
#pragma unroll
      for (int nt = 0; nt < 4; ++nt) {
        float vv = s[nt][r] * C;
        if (kt == qt && nt == w && l16 > quad * 4 + r) vv = -INFINITY;
        v[nt] = vv;
      }
      float mx = fmaxf(fmaxf(v[0], v[1]), fmaxf(v[2], v[3]));
#pragma unroll
      for (int d = 1; d < 16; d <<= 1) mx = fmaxf(mx, __shfl_xor(mx, d, 64));
      float mnew = fmaxf(m_[r], mx);
      float a0 = __builtin_amdgcn_exp2f(m_[r] - mnew);
      float sum = 0.f;
#pragma unroll
      for (int nt = 0; nt < 4; ++nt) {
        p[nt][r] = __builtin_amdgcn_exp2f(v[nt] - mnew);
        sum += p[nt][r];
      }
#pragma unroll
      for (int d = 1; d < 16; d <<= 1) sum += __shfl_xor(sum, d, 64);
      l_[r] = l_[r] * a0 + sum;
      m_[r] = mnew;
      al[r] = a0;
    }
#pragma unroll
    for (int dt = 0; dt < 8; ++dt)
#pragma unroll
      for (int r = 0; r < 4; ++r) o_[dt][r] *= al[r];

    // ---- P -> per-wave LDS (C/D -> A-operand layout), no block barrier ----
#pragma unroll
    for (int r = 0; r < 4; ++r)
#pragma unroll
      for (int nt = 0; nt < 4; ++nt)
        ((ushort_t*)psw)[(quad * 4 + r) * 72 + nt * 16 + l16] = f2bf(p[nt][r]);
    asm volatile("s_waitcnt lgkmcnt(0)" ::: "memory");
    bf16x8 pf[2];
#pragma unroll
    for (int kc = 0; kc < 2; ++kc)
      pf[kc] = *(const bf16x8*)(psw + l16 * 144 + kc * 64 + quad * 16);

    // ---- O += P V : 8 d-tiles x 2 k-chunks ----
#pragma unroll
    for (int dt = 0; dt < 8; ++dt) {
#pragma unroll
      for (int kc = 0; kc < 2; ++kc) {
        bf16x8 vf = *(const bf16x8*)(Vs + (dt * 16 + l16) * 128 +
                                     (((kc * 4 + quad) ^ (l16 & 7)) * 16));
        o_[dt] = MFMA16(pf[kc], vf, o_[dt]);
      }
    }
  }

  // ---- epilogue: normalize, store bf16 (b,s,h,d) ----
#pragma unroll
  for (int r = 0; r < 4; ++r) {
    float linv = 1.0f / l_[r];
    size_t base = (size_t)(b * S_ + q0 + w * 16 + quad * 4 + r) * QDIM + h * HD_;
#pragma unroll
    for (int dt = 0; dt < 8; ++dt)
      ob[base + dt * 16 + l16] = f2bf(o_[dt][r] * linv);
  }
}

// ---------------------------------------------------------------------------
// Launch. Workspace layout (MiB offsets), 160 MiB total:
//   0: xb(32, reused for wob) | 32: wqb(32) | 64: wkb(8) | 72: wvb(8)
//  80: qbuf(32) | 112: kbuf(8) | 120: vtb(8) | 128: attnb(32)
// ---------------------------------------------------------------------------
extern "C" void kernel_launch(void* const* d_in, const int* in_sizes, int n_in,
                              void* d_out, int out_size, void* d_ws, size_t ws_size,
                              hipStream_t stream) {
  const float* x  = (const float*)d_in[0];
  const float* wq = (const float*)d_in[1];
  const float* wk = (const float*)d_in[2];
  const float* wv = (const float*)d_in[3];
  const float* wo = (const float*)d_in[4];
  const float* fc = (const float*)d_in[5];
  const float* fs = (const float*)d_in[6];
  float* out = (float*)d_out;

  char* ws = (char*)d_ws;
  ushort_t* xb    = (ushort_t*)(ws);
  ushort_t* wqb   = (ushort_t*)(ws + (32ull << 20));
  ushort_t* wkb   = (ushort_t*)(ws + (64ull << 20));
  ushort_t* wvb   = (ushort_t*)(ws + (72ull << 20));
  ushort_t* qbuf  = (ushort_t*)(ws + (80ull << 20));
  ushort_t* kbuf  = (ushort_t*)(ws + (112ull << 20));
  ushort_t* vtb   = (ushort_t*)(ws + (120ull << 20));
  ushort_t* attnb = (ushort_t*)(ws + (128ull << 20));
  ushort_t* wob   = xb;  // x dead after projections

  dim3 blk(256);

  conv_f32_bf16<<<(MROWS * DIM_) / 2048, blk, 0, stream>>>(x, xb);
  conv_f32_bf16<<<(QDIM * DIM_) / 2048, blk, 0, stream>>>(wq, wqb);
  conv_f32_bf16<<<(KVDIM * DIM_) / 2048, blk, 0, stream>>>(wk, wkb);
  conv_f32_bf16<<<(KVDIM * DIM_) / 2048, blk, 0, stream>>>(wv, wvb);

  gemm_bf16<0><<<dim3(QDIM / 128, MROWS / 128), blk, 0, stream>>>(xb, wqb, qbuf, MROWS, QDIM, DIM_);
  gemm_bf16<0><<<dim3(KVDIM / 128, MROWS / 128), blk, 0, stream>>>(xb, wkb, kbuf, MROWS, KVDIM, DIM_);
  gemm_bf16<2><<<dim3(KVDIM / 128, MROWS / 128), blk, 0, stream>>>(xb, wvb, vtb, MROWS, KVDIM, DIM_);

  rope_bf16<<<(MROWS * (NH_ + NKV_) * 16) / 256, blk, 0, stream>>>(qbuf, kbuf, fc, fs);

  attn_mfma<<<dim3(S_ / 64, NH_, B_), blk, 0, stream>>>(qbuf, kbuf, vtb, attnb);

  conv_f32_bf16<<<(QDIM * DIM_) / 2048, blk, 0, stream>>>(wo, wob);
  gemm_bf16<1><<<dim3(QDIM / 128, MROWS / 128), blk, 0, stream>>>(attnb, wob, out, MROWS, QDIM, DIM_);
}